// Round 2
// baseline (1041.514 us; speedup 1.0000x reference)
//
#include <hip/hip_runtime.h>

// E2V layer, decomposed:
//   proj[e][0:64]   = hyperedge[e] @ W0^T + b      (precomputed per edge, f32, in d_ws)
//   proj[e][64:128] = hyperedge[e] @ W1^T
//   out[n] = relu( proj[i0[n]][0:64] + proj[i1[n]][64:128] + node[n] @ W2^T )
// Round 2: 2-tile unroll (32 incidences / wave-iter) for 2x memory-level parallelism,
// gathers folded into the MFMA C operand (short live ranges), non-temporal loads for
// streaming operands (node, aff) and non-temporal stores for out so L2 stays
// dedicated to the proj gather table.

typedef __bf16 bf16x8 __attribute__((ext_vector_type(8)));
typedef float  f32x4  __attribute__((ext_vector_type(4)));

static __device__ __forceinline__ bf16x8 cvt8(f32x4 a, f32x4 b) {
  bf16x8 r;
  r[0] = (__bf16)a[0]; r[1] = (__bf16)a[1]; r[2] = (__bf16)a[2]; r[3] = (__bf16)a[3];
  r[4] = (__bf16)b[0]; r[5] = (__bf16)b[1]; r[6] = (__bf16)b[2]; r[7] = (__bf16)b[3];
  return r;
}

static __device__ __forceinline__ bf16x8 load_frag(const float* __restrict__ p) {
  f32x4 a = *(const f32x4*)p;
  f32x4 b = *(const f32x4*)(p + 4);
  return cvt8(a, b);
}

static __device__ __forceinline__ bf16x8 load_frag_nt(const float* __restrict__ p) {
  f32x4 a = __builtin_nontemporal_load((const f32x4*)p);
  f32x4 b = __builtin_nontemporal_load((const f32x4*)(p + 4));
  return cvt8(a, b);
}

#define N_EDGES  100000
#define N_INC    2000000
#define N_TILES  (N_INC / 16)    // 125000
#define P_TILES  (N_TILES / 2)   // 62500 tile-pairs (32 incidences each)
#define E_TILES  (N_EDGES / 16)  // 6250

// ---------------------------------------------------------------------------
// Kernel 1: per-edge projections. proj row layout: [128] = [W0-part+bias | W1-part]
// ---------------------------------------------------------------------------
__global__ __launch_bounds__(256, 2) void edge_proj(
    const float* __restrict__ hyperedge,  // [100000, 64]
    const float* __restrict__ W,          // [64, 192]
    const float* __restrict__ bias,       // [64]
    float*       __restrict__ proj)       // [100000, 128]
{
  const int lane = threadIdx.x & 63;
  const int wid  = (blockIdx.x * blockDim.x + threadIdx.x) >> 6;
  if (wid >= E_TILES) return;
  const int m    = lane & 15;
  const int quad = lane >> 4;
  const int koff = quad * 8;

  bf16x8 Wf[8][2];
  #pragma unroll
  for (int t = 0; t < 8; ++t) {
    const float* wr = W + (long)((t & 3) * 16 + m) * 192 + (t >> 2) * 64 + koff;
    #pragma unroll
    for (int f = 0; f < 2; ++f)
      Wf[t][f] = load_frag(wr + f * 32);
  }

  const int ebase = wid * 16;
  const float* er = hyperedge + (long)(ebase + m) * 64 + koff;
  bf16x8 hef0 = load_frag(er);
  bf16x8 hef1 = load_frag(er + 32);

  f32x4 acc[8] = { {0,0,0,0},{0,0,0,0},{0,0,0,0},{0,0,0,0},
                   {0,0,0,0},{0,0,0,0},{0,0,0,0},{0,0,0,0} };
  #pragma unroll
  for (int t = 0; t < 8; ++t) {
    acc[t] = __builtin_amdgcn_mfma_f32_16x16x32_bf16(Wf[t][0], hef0, acc[t], 0, 0, 0);
    acc[t] = __builtin_amdgcn_mfma_f32_16x16x32_bf16(Wf[t][1], hef1, acc[t], 0, 0, 0);
  }

  float* pr = proj + (long)(ebase + m) * 128 + quad * 4;
  #pragma unroll
  for (int t = 0; t < 8; ++t) {
    f32x4 v = acc[t];
    if (t < 4) {
      f32x4 bv = *(const f32x4*)(bias + t * 16 + quad * 4);
      v[0] += bv[0]; v[1] += bv[1]; v[2] += bv[2]; v[3] += bv[3];
    }
    *(f32x4*)(pr + t * 16) = v;
  }
}

// ---------------------------------------------------------------------------
// Kernel 2: main. Per tile-pair (32 incidences): gathers init the MFMA C operand,
// node@W2^T accumulates on top, relu, nt dwordx4 stores.
// ---------------------------------------------------------------------------
__global__ __launch_bounds__(256, 4) void e2v_gather(
    const float* __restrict__ hyper_node, // [N_INC, 64]
    const int*   __restrict__ aff,        // [2, N_INC]
    const float* __restrict__ W,          // [64, 192]
    const float* __restrict__ proj,       // [100000, 128]
    float*       __restrict__ out)        // [N_INC, 64]
{
  const int lane = threadIdx.x & 63;
  const int wid  = (blockIdx.x * blockDim.x + threadIdx.x) >> 6;
  const int nw   = (gridDim.x * blockDim.x) >> 6;
  const int m    = lane & 15;
  const int quad = lane >> 4;
  const int koff = quad * 8;

  // W2 fragments (A-operand, channel blocks): W2[c][k] = W[c][128+k]
  bf16x8 Wf2[4][2];
  #pragma unroll
  for (int t = 0; t < 4; ++t) {
    const float* wr = W + (long)(t * 16 + m) * 192 + 128 + koff;
    #pragma unroll
    for (int f = 0; f < 2; ++f)
      Wf2[t][f] = load_frag(wr + f * 32);
  }

  const int* __restrict__ aff0 = aff;
  const int* __restrict__ aff1 = aff + N_INC;

  int p = wid;
  if (p >= P_TILES) return;

  // prefetched indices for the current pair (tiles 2p and 2p+1)
  long pba = (long)p * 32 + m;
  int ci_a0 = __builtin_nontemporal_load(aff0 + pba);
  int ci_b0 = __builtin_nontemporal_load(aff0 + pba + 16);
  int ci_a1 = __builtin_nontemporal_load(aff1 + pba);
  int ci_b1 = __builtin_nontemporal_load(aff1 + pba + 16);

  for (; p < P_TILES; p += nw) {
    const int ia0 = ci_a0, ia1 = ci_a1, ib0 = ci_b0, ib1 = ci_b1;
    const int nb = p * 32;

    // prefetch next pair's indices (breaks the aff->gather serial chain)
    const int np = p + nw;
    if (np < P_TILES) {
      const long pb = (long)np * 32 + m;
      ci_a0 = __builtin_nontemporal_load(aff0 + pb);
      ci_b0 = __builtin_nontemporal_load(aff0 + pb + 16);
      ci_a1 = __builtin_nontemporal_load(aff1 + pb);
      ci_b1 = __builtin_nontemporal_load(aff1 + pb + 16);
    }

    // issue all 16 gathers (both tiles) — 64B contiguous per row per instr
    const float* pa0 = proj + (long)ia0 * 128 + quad * 4;
    const float* pa1 = proj + (long)ia1 * 128 + 64 + quad * 4;
    const float* pb0 = proj + (long)ib0 * 128 + quad * 4;
    const float* pb1 = proj + (long)ib1 * 128 + 64 + quad * 4;
    f32x4 ga0[4], ga1[4], gb0[4], gb1[4];
    #pragma unroll
    for (int t = 0; t < 4; ++t) {
      ga0[t] = *(const f32x4*)(pa0 + t * 16);
      ga1[t] = *(const f32x4*)(pa1 + t * 16);
      gb0[t] = *(const f32x4*)(pb0 + t * 16);
      gb1[t] = *(const f32x4*)(pb1 + t * 16);
    }

    // node fragments for both tiles (B-operand: col = incidence), stream-once -> nt
    const float* nda = hyper_node + (long)(nb + m) * 64 + koff;
    const float* ndb = nda + 16 * 64;
    bf16x8 Na0 = load_frag_nt(nda);
    bf16x8 Na1 = load_frag_nt(nda + 32);
    bf16x8 Nb0 = load_frag_nt(ndb);
    bf16x8 Nb1 = load_frag_nt(ndb + 32);

    // ---- tile a: C := ga0 + ga1, then accumulate node@W2^T
    f32x4 acca[4];
    #pragma unroll
    for (int t = 0; t < 4; ++t) acca[t] = ga0[t] + ga1[t];
    #pragma unroll
    for (int t = 0; t < 4; ++t)
      acca[t] = __builtin_amdgcn_mfma_f32_16x16x32_bf16(Wf2[t][0], Na0, acca[t], 0, 0, 0);
    #pragma unroll
    for (int t = 0; t < 4; ++t)
      acca[t] = __builtin_amdgcn_mfma_f32_16x16x32_bf16(Wf2[t][1], Na1, acca[t], 0, 0, 0);

    float* opa = out + (long)(nb + m) * 64 + quad * 4;
    #pragma unroll
    for (int t = 0; t < 4; ++t) {
      f32x4 v = acca[t];
      #pragma unroll
      for (int r = 0; r < 4; ++r) v[r] = v[r] > 0.f ? v[r] : 0.f;
      __builtin_nontemporal_store(v, (f32x4*)(opa + t * 16));
    }

    // ---- tile b
    f32x4 accb[4];
    #pragma unroll
    for (int t = 0; t < 4; ++t) accb[t] = gb0[t] + gb1[t];
    #pragma unroll
    for (int t = 0; t < 4; ++t)
      accb[t] = __builtin_amdgcn_mfma_f32_16x16x32_bf16(Wf2[t][0], Nb0, accb[t], 0, 0, 0);
    #pragma unroll
    for (int t = 0; t < 4; ++t)
      accb[t] = __builtin_amdgcn_mfma_f32_16x16x32_bf16(Wf2[t][1], Nb1, accb[t], 0, 0, 0);

    float* opb = opa + 16 * 64;
    #pragma unroll
    for (int t = 0; t < 4; ++t) {
      f32x4 v = accb[t];
      #pragma unroll
      for (int r = 0; r < 4; ++r) v[r] = v[r] > 0.f ? v[r] : 0.f;
      __builtin_nontemporal_store(v, (f32x4*)(opb + t * 16));
    }
  }
}

// ---------------------------------------------------------------------------
// Fallback (fused 192-K): used only if workspace is too small.
// ---------------------------------------------------------------------------
__global__ __launch_bounds__(256, 2) void e2v_mfma(
    const float* __restrict__ hyperedge,
    const float* __restrict__ hyper_node,
    const int*   __restrict__ aff,
    const float* __restrict__ W,
    const float* __restrict__ bias,
    float*       __restrict__ out)
{
  const int lane = threadIdx.x & 63;
  const int wid  = (blockIdx.x * blockDim.x + threadIdx.x) >> 6;
  const int nw   = (gridDim.x * blockDim.x) >> 6;
  const int m    = lane & 15;
  const int quad = lane >> 4;
  const int koff = quad * 8;

  bf16x8 Bf[4][6];
  #pragma unroll
  for (int t = 0; t < 4; ++t) {
    const float* wr = W + (t * 16 + m) * 192 + koff;
    #pragma unroll
    for (int f = 0; f < 6; ++f)
      Bf[t][f] = load_frag(wr + f * 32);
  }
  float bv[4];
  #pragma unroll
  for (int t = 0; t < 4; ++t) bv[t] = bias[t * 16 + m];

  const int* __restrict__ aff0 = aff;
  const int* __restrict__ aff1 = aff + N_INC;

  for (int tile = wid; tile < N_TILES; tile += nw) {
    const int n_base = tile * 16;
    const int i0 = aff0[n_base + m];
    const int i1 = aff1[n_base + m];
    const float* e0 = hyperedge  + (long)i0 * 64 + koff;
    const float* e1 = hyperedge  + (long)i1 * 64 + koff;
    const float* nd = hyper_node + (long)(n_base + m) * 64 + koff;

    bf16x8 A[6];
    A[0] = load_frag(e0);
    A[1] = load_frag(e0 + 32);
    A[2] = load_frag(e1);
    A[3] = load_frag(e1 + 32);
    A[4] = load_frag(nd);
    A[5] = load_frag(nd + 32);

    f32x4 acc[4] = { {0.f,0.f,0.f,0.f}, {0.f,0.f,0.f,0.f},
                     {0.f,0.f,0.f,0.f}, {0.f,0.f,0.f,0.f} };
    #pragma unroll
    for (int f = 0; f < 6; ++f) {
      #pragma unroll
      for (int t = 0; t < 4; ++t)
        acc[t] = __builtin_amdgcn_mfma_f32_16x16x32_bf16(A[f], Bf[t][f], acc[t], 0, 0, 0);
    }

    #pragma unroll
    for (int t = 0; t < 4; ++t) {
      const int o = t * 16 + m;
      #pragma unroll
      for (int r = 0; r < 4; ++r) {
        const int inc = n_base + quad * 4 + r;
        float v = acc[t][r] + bv[t];
        out[(long)inc * 64 + o] = v > 0.f ? v : 0.f;
      }
    }
  }
}

extern "C" void kernel_launch(void* const* d_in, const int* in_sizes, int n_in,
                              void* d_out, int out_size, void* d_ws, size_t ws_size,
                              hipStream_t stream) {
  const float* hyperedge  = (const float*)d_in[0];
  const float* hyper_node = (const float*)d_in[1];
  const int*   aff        = (const int*)d_in[2];
  const float* W          = (const float*)d_in[3];
  const float* bias       = (const float*)d_in[4];
  float* out = (float*)d_out;

  const size_t need = (size_t)N_EDGES * 128 * sizeof(float);  // 51.2 MB
  if (ws_size >= need) {
    float* proj = (float*)d_ws;
    hipLaunchKernelGGL(edge_proj, dim3((E_TILES * 64 + 255) / 256), dim3(256), 0, stream,
                       hyperedge, W, bias, proj);
    hipLaunchKernelGGL(e2v_gather, dim3(4096), dim3(256), 0, stream,
                       hyper_node, aff, W, proj, out);
  } else {
    hipLaunchKernelGGL(e2v_mfma, dim3(4096), dim3(256), 0, stream,
                       hyperedge, hyper_node, aff, W, bias, out);
  }
}